// Round 1
// baseline (87.046 us; speedup 1.0000x reference)
//
#include <hip/hip_runtime.h>

// DWN fused kernel: thermometer-encode -> binary LUT layer (pure lookup) ->
// continuous 6-D multilinear LUT layer -> group-sum/tau.
// One block per batch row; all intermediates live in LDS.

#define BATCH 512
#define FEAT  1024
#define NTHR  3
#define NBITS (FEAT * NTHR)   // 3072
#define O1    2000
#define O2    1000
#define NCLS  10

__global__ __launch_bounds__(256) void dwn_fused(
    const float* __restrict__ x,       // [512,1024]
    const float* __restrict__ thr,     // [1024,3]
    const float* __restrict__ luts1,   // [2000,64]
    const int*   __restrict__ idx1,    // [2000,6] in [0,3072)
    const float* __restrict__ luts2,   // [1000,64]
    const int*   __restrict__ idx2,    // [1000,6] in [0,2000)
    float* __restrict__ out)           // [512,10]
{
    __shared__ unsigned char s_bits[NBITS]; // 3 KB
    __shared__ float s_h1[O1];              // 8 KB
    __shared__ float s_h2[O2];              // 4 KB

    const int b = blockIdx.x;
    const int t = threadIdx.x;

    // ---- Phase 1: thermometer encode (binary bits) ----
    for (int f = t; f < FEAT; f += 256) {
        float xv = x[b * FEAT + f];
        s_bits[f * 3 + 0] = (unsigned char)(xv > thr[f * 3 + 0]);
        s_bits[f * 3 + 1] = (unsigned char)(xv > thr[f * 3 + 1]);
        s_bits[f * 3 + 2] = (unsigned char)(xv > thr[f * 3 + 2]);
    }
    __syncthreads();

    // ---- Phase 2: layer 1 — binary inputs => pure 6-bit table lookup ----
    // Reference fold: step k selects upper half (offset 2^(5-k)) when x_k==1,
    // so final index = sum_k bit_k << (5-k).
    for (int o = t; o < O1; o += 256) {
        const int* ip = idx1 + o * 6;
        int code = 0;
#pragma unroll
        for (int k = 0; k < 6; ++k)
            code |= ((int)s_bits[ip[k]]) << (5 - k);
        s_h1[o] = luts1[o * 64 + code];
    }
    __syncthreads();

    // ---- Phase 3: layer 2 — true multilinear interpolation over 64 entries.
    // Entry i bit (5-k) pairs with x_k; multilinear weights commute, so fold
    // LSB-first: fold x5,x4 inside each float4 load, then x3,x2,x1,x0.
    for (int o = t; o < O2; o += 256) {
        const int* ip = idx2 + o * 6;
        float xv0 = s_h1[ip[0]];
        float xv1 = s_h1[ip[1]];
        float xv2 = s_h1[ip[2]];
        float xv3 = s_h1[ip[3]];
        float xv4 = s_h1[ip[4]];
        float xv5 = s_h1[ip[5]];

        const float4* lp = (const float4*)(luts2 + (size_t)o * 64);
        float v[16];
#pragma unroll
        for (int q = 0; q < 16; ++q) {   // fold x5 (bit0), x4 (bit1)
            float4 e = lp[q];
            float u0 = e.x + xv5 * (e.y - e.x);
            float u1 = e.z + xv5 * (e.w - e.z);
            v[q] = u0 + xv4 * (u1 - u0);
        }
#pragma unroll
        for (int q = 0; q < 8; ++q) v[q] = v[2*q] + xv3 * (v[2*q+1] - v[2*q]);
#pragma unroll
        for (int q = 0; q < 4; ++q) v[q] = v[2*q] + xv2 * (v[2*q+1] - v[2*q]);
#pragma unroll
        for (int q = 0; q < 2; ++q) v[q] = v[2*q] + xv1 * (v[2*q+1] - v[2*q]);
        s_h2[o] = v[0] + xv0 * (v[1] - v[0]);
    }
    __syncthreads();

    // ---- Phase 4: group sum / tau ----
    if (t < NCLS) {
        float s = 0.0f;
#pragma unroll 4
        for (int j = 0; j < 100; ++j) s += s_h2[t * 100 + j];
        out[b * NCLS + t] = s / 3.3333333f;
    }
}

extern "C" void kernel_launch(void* const* d_in, const int* in_sizes, int n_in,
                              void* d_out, int out_size, void* d_ws, size_t ws_size,
                              hipStream_t stream) {
    const float* x      = (const float*)d_in[0];
    const float* thr    = (const float*)d_in[1];
    const float* luts1  = (const float*)d_in[2];
    const int*   idx1   = (const int*)  d_in[3];
    const float* luts2  = (const float*)d_in[4];
    const int*   idx2   = (const int*)  d_in[5];
    float* out = (float*)d_out;

    dwn_fused<<<BATCH, 256, 0, stream>>>(x, thr, luts1, idx1, luts2, idx2, out);
}

// Round 2
// 79.610 us; speedup vs baseline: 1.0934x; 1.0934x over previous
//
#include <hip/hip_runtime.h>

// DWN fused kernel, G=2 batch rows per block:
// thermometer-encode -> binary LUT layer (pure 6-bit lookup) ->
// continuous 6-D multilinear LUT layer -> group-sum/tau.
// Lane pairs (2j,2j+1) share one `o` across the two batch rows, so each
// idx1/luts1/idx2/luts2 cache line is read once per block (broadcast),
// halving the L2 rebroadcast traffic vs block-per-row (131 MB -> 65 MB).

#define BATCH 512
#define FEAT  1024
#define NBITS (FEAT * 3)   // 3072
#define O1    2000
#define O2    1000
#define NCLS  10
#define G     2            // batch rows per block
#define NT    512          // threads per block (8 waves)

__global__ __launch_bounds__(NT) void dwn_fused2(
    const float* __restrict__ x,       // [512,1024]
    const float* __restrict__ thr,     // [1024,3]
    const float* __restrict__ luts1,   // [2000,64]
    const int*   __restrict__ idx1,    // [2000,6] in [0,3072)
    const float* __restrict__ luts2,   // [1000,64]
    const int*   __restrict__ idx2,    // [1000,6] in [0,2000)
    float* __restrict__ out)           // [512,10]
{
    __shared__ unsigned char s_bits[G][NBITS]; // 6 KB
    __shared__ float s_h1[G][O1];              // 16 KB
    __shared__ float s_h2[G][O2];              // 8 KB
    __shared__ float s_part[G * NCLS * 10];    // 800 B

    const int b0 = blockIdx.x * G;
    const int t  = threadIdx.x;

    // ---- Phase 1: thermometer encode for G rows ----
    for (int i = t; i < G * FEAT; i += NT) {
        int r = i >> 10;          // FEAT = 1024
        int f = i & (FEAT - 1);
        float xv = x[(b0 + r) * FEAT + f];
        const float* tp = thr + f * 3;
        s_bits[r][f * 3 + 0] = (unsigned char)(xv > tp[0]);
        s_bits[r][f * 3 + 1] = (unsigned char)(xv > tp[1]);
        s_bits[r][f * 3 + 2] = (unsigned char)(xv > tp[2]);
    }
    __syncthreads();

    // ---- Phase 2: layer 1 — binary inputs => pure 6-bit table lookup ----
    // i -> (o = i>>1, r = i&1): lane pairs share the idx1 row and luts1 row.
    for (int i = t; i < G * O1; i += NT) {
        int o = i >> 1;
        int r = i & 1;
        const int2* ip = (const int2*)(idx1 + o * 6);   // o*24 is 8B-aligned
        int2 p0 = ip[0], p1 = ip[1], p2 = ip[2];
        int code = ((int)s_bits[r][p0.x] << 5) | ((int)s_bits[r][p0.y] << 4)
                 | ((int)s_bits[r][p1.x] << 3) | ((int)s_bits[r][p1.y] << 2)
                 | ((int)s_bits[r][p2.x] << 1) |  (int)s_bits[r][p2.y];
        s_h1[r][o] = luts1[o * 64 + code];
    }
    __syncthreads();

    // ---- Phase 3: layer 2 — 6-D multilinear interpolation, LSB-first fold.
    // Lane pairs share the 256 B luts2 row (one L2 fetch, broadcast).
    for (int i = t; i < G * O2; i += NT) {
        int o = i >> 1;
        int r = i & 1;
        const int2* ip = (const int2*)(idx2 + o * 6);
        int2 p0 = ip[0], p1 = ip[1], p2 = ip[2];
        float xv0 = s_h1[r][p0.x];
        float xv1 = s_h1[r][p0.y];
        float xv2 = s_h1[r][p1.x];
        float xv3 = s_h1[r][p1.y];
        float xv4 = s_h1[r][p2.x];
        float xv5 = s_h1[r][p2.y];

        const float4* lp = (const float4*)(luts2 + (size_t)o * 64);
        float v[16];
#pragma unroll
        for (int q = 0; q < 16; ++q) {   // fold x5 (bit0), x4 (bit1)
            float4 e = lp[q];
            float u0 = e.x + xv5 * (e.y - e.x);
            float u1 = e.z + xv5 * (e.w - e.z);
            v[q] = u0 + xv4 * (u1 - u0);
        }
#pragma unroll
        for (int q = 0; q < 8; ++q) v[q] = v[2*q] + xv3 * (v[2*q+1] - v[2*q]);
#pragma unroll
        for (int q = 0; q < 4; ++q) v[q] = v[2*q] + xv2 * (v[2*q+1] - v[2*q]);
#pragma unroll
        for (int q = 0; q < 2; ++q) v[q] = v[2*q] + xv1 * (v[2*q+1] - v[2*q]);
        s_h2[r][o] = v[0] + xv0 * (v[1] - v[0]);
    }
    __syncthreads();

    // ---- Phase 4: group sum / tau, two-level reduction ----
    if (t < G * NCLS * 10) {             // 200 partial sums of 10
        int g = t / 10;                  // (r*NCLS + cls)
        int p = t % 10;
        int r   = g / NCLS;
        int cls = g % NCLS;
        const float* hp = &s_h2[r][cls * 100 + p * 10];
        float s = 0.0f;
#pragma unroll
        for (int j = 0; j < 10; ++j) s += hp[j];
        s_part[t] = s;
    }
    __syncthreads();
    if (t < G * NCLS) {                  // 20 final sums of 10 partials
        float s = 0.0f;
#pragma unroll
        for (int j = 0; j < 10; ++j) s += s_part[t * 10 + j];
        int r   = t / NCLS;
        int cls = t % NCLS;
        out[(b0 + r) * NCLS + cls] = s / 3.3333333f;
    }
}

extern "C" void kernel_launch(void* const* d_in, const int* in_sizes, int n_in,
                              void* d_out, int out_size, void* d_ws, size_t ws_size,
                              hipStream_t stream) {
    const float* x      = (const float*)d_in[0];
    const float* thr    = (const float*)d_in[1];
    const float* luts1  = (const float*)d_in[2];
    const int*   idx1   = (const int*)  d_in[3];
    const float* luts2  = (const float*)d_in[4];
    const int*   idx2   = (const int*)  d_in[5];
    float* out = (float*)d_out;

    dwn_fused2<<<BATCH / G, NT, 0, stream>>>(x, thr, luts1, idx1, luts2, idx2, out);
}